// Round 6
// baseline (132.118 us; speedup 1.0000x reference)
//
#include <hip/hip_runtime.h>
#include <hip/hip_fp16.h>

#define BS 2
#define NS 50000
#define CCH 32
#define RR 128
#define SS 8

typedef float v2f __attribute__((ext_vector_type(2)));
typedef _Float16 h2 __attribute__((ext_vector_type(2)));

#if __has_builtin(__builtin_amdgcn_fdot2)
#define HAVE_DOT2 1
#else
#define HAVE_DOT2 0
#endif

// ws layout (pair-replicated fp16 planes):
//   tp : BS*3*RR*RR blocks of 128 B:
//        block (b,pl,y,x) holds channels c=0..31 interleaved {col x, col x+1}:
//        uint32 #c = half(src[c][y][x]) | half(src[c][y][min(x+1,127)])<<16
//   Wc : 1024 floats  (W_v @ W_out)
//   bvw: 32 floats    (b_v @ W_out)

__device__ __forceinline__ unsigned pk_rn(float a, float b) {
    unsigned h0 = __half_as_ushort(__float2half(a));
    unsigned h1 = __half_as_ushort(__float2half(b));
    return h0 | (h1 << 16);
}

__global__ __launch_bounds__(256)
void prep(const float* __restrict__ cxz,
          const float* __restrict__ cxy,
          const float* __restrict__ cyz,
          const float* __restrict__ Wv, const float* __restrict__ bv,
          const float* __restrict__ Wout,
          unsigned* __restrict__ tp, float* __restrict__ Wc,
          float* __restrict__ bvw) {
    __shared__ float lds[32 * 129];
    int tid = threadIdx.x;
    int row = blockIdx.x;
    if (row < BS * 3 * RR) {
        int y  = row & 127;
        int pl = (row >> 7) % 3;
        int b  = row / 384;
        const float* src = (pl == 0) ? cxz : ((pl == 1) ? cxy : cyz);
        const float* sp = src + (((size_t)(b * CCH)) << 14) + (y << 7);
        int c = tid >> 3, xq = tid & 7;
        const float4* s4 = (const float4*)(sp + ((size_t)c << 14));
#pragma unroll
        for (int k = 0; k < 4; ++k) {
            float4 v = s4[xq + 8 * k];
            int x = (xq + 8 * k) << 2;
            lds[c * 129 + x + 0] = v.x;
            lds[c * 129 + x + 1] = v.y;
            lds[c * 129 + x + 2] = v.z;
            lds[c * 129 + x + 3] = v.w;
        }
        __syncthreads();
        uint4* dst = (uint4*)(tp + ((size_t)row << 12));
#pragma unroll
        for (int i = 0; i < 4; ++i) {
            int j = tid + 256 * i;          // uint4 index 0..1023
            int x  = j >> 3;
            int c0 = (j & 7) << 2;          // channels c0..c0+3 at column x
            int x1 = min(x + 1, 127);
            uint4 o;
            o.x = pk_rn(lds[(c0 + 0) * 129 + x], lds[(c0 + 0) * 129 + x1]);
            o.y = pk_rn(lds[(c0 + 1) * 129 + x], lds[(c0 + 1) * 129 + x1]);
            o.z = pk_rn(lds[(c0 + 2) * 129 + x], lds[(c0 + 2) * 129 + x1]);
            o.w = pk_rn(lds[(c0 + 3) * 129 + x], lds[(c0 + 3) * 129 + x1]);
            dst[j] = o;
        }
    } else {
        int t = (row - BS * 3 * RR) * 256 + tid;    // 0..1023
        int c = t >> 5, j = t & 31;
        float acc = 0.f;
#pragma unroll
        for (int k = 0; k < 32; ++k) acc += Wv[c * 32 + k] * Wout[k * 32 + j];
        Wc[t] = acc;
        if (t < 32) {
            float a2 = 0.f;
#pragma unroll
            for (int k = 0; k < 32; ++k) a2 += bv[k] * Wout[k * 32 + t];
            bvw[t] = a2;
        }
    }
}

// ---- main kernel: 8 lanes/query, lane owns channels 4l..4l+3.
// All intra-group broadcasts go through per-query LDS slots (broadcast reads)
// instead of ds_bpermute shuffles: producer and consumers are the SAME wave,
// so no barriers are needed (compiler-tracked lgkmcnt ordering).
// Tap addressing: wave-uniform base + 32-bit byte offsets.
// Byte offsets: plane stride 1<<21, y stride 1<<14, x stride 1<<7.

struct f4 { v2f lo, hi; };   // 4 channels

struct Coord {
    int o0, o1, o2, o3, o4, o5;
    float wc0, wc1, wr1, wr2;
};

__device__ __forceinline__ Coord coord(float p0, float p1, float p2) {
    Coord c;
    float x0c = fminf(fmaxf(p0, 0.f), 1.f) * 127.f;
    int i0 = min((int)x0c, 126);
    c.wc0 = x0c - (float)i0;
    float x1c = fminf(fmaxf(p1, 0.f), 1.f) * 127.f;
    int i1 = min((int)x1c, 126);
    c.wc1 = x1c - (float)i1;
    float f1 = floorf(x1c);
    int r10 = (int)f1, r11 = min(r10 + 1, 127);
    c.wr1 = x1c - f1;
    float x2c = fminf(fmaxf(p2, 0.f), 1.f) * 127.f;
    float f2 = floorf(x2c);
    int r20 = (int)f2, r21 = min(r20 + 1, 127);
    c.wr2 = x2c - f2;
    int c0 = i0 << 7, c1 = i1 << 7;
    c.o0 = (r20 << 14) + c0;
    c.o1 = (r21 << 14) + c0;
    c.o2 = (1 << 21) + (r10 << 14) + c0;
    c.o3 = (1 << 21) + (r11 << 14) + c0;
    c.o4 = (2 << 21) + (r20 << 14) + c1;
    c.o5 = (2 << 21) + (r21 << 14) + c1;
    return c;
}

__device__ __forceinline__ uint4 ldtap(const char* __restrict__ tpb, int off) {
    return *(const uint4*)(tpb + off);
}

struct SampB { uint4 u[6]; };   // in-flight tap data (24 VGPR)

__device__ __forceinline__ unsigned pack2(float a, float b) {
#if HAVE_DOT2
    return __builtin_bit_cast(unsigned, __builtin_amdgcn_cvt_pkrtz(a, b));
#else
    __half2 h = __floats2half2_rn(a, b);
    return __builtin_bit_cast(unsigned, h);
#endif
}

#if HAVE_DOT2
__device__ __forceinline__ void eval_row(f4& acc, uint4 u, h2 w) {
    acc.lo.x = __builtin_amdgcn_fdot2(__builtin_bit_cast(h2, u.x), w, acc.lo.x, false);
    acc.lo.y = __builtin_amdgcn_fdot2(__builtin_bit_cast(h2, u.y), w, acc.lo.y, false);
    acc.hi.x = __builtin_amdgcn_fdot2(__builtin_bit_cast(h2, u.z), w, acc.hi.x, false);
    acc.hi.y = __builtin_amdgcn_fdot2(__builtin_bit_cast(h2, u.w), w, acc.hi.y, false);
}

__device__ __forceinline__ void eval_plane(f4& acc, uint4 ua, uint4 ub,
                                           float wx, float wy) {
    float wB1 = wx * wy;          // (x1,y1)
    float wB0 = wx - wB1;         // (x1,y0)
    float wA1 = wy - wB1;         // (x0,y1)
    float wA0 = 1.f - wx - wA1;   // (x0,y0)
    h2 w0 = __builtin_bit_cast(h2, __builtin_amdgcn_cvt_pkrtz(wA0, wB0));
    h2 w1 = __builtin_bit_cast(h2, __builtin_amdgcn_cvt_pkrtz(wA1, wB1));
    eval_row(acc, ua, w0);
    eval_row(acc, ub, w1);
}

__device__ __forceinline__ void eval_rowp(f4& acc, uint4 u, unsigned pw) {
    eval_row(acc, u, __builtin_bit_cast(h2, pw));
}

__device__ __forceinline__ void dot2_4(f4& acc, uint4 wv, unsigned pw) {
    h2 w = __builtin_bit_cast(h2, pw);
    acc.lo.x = __builtin_amdgcn_fdot2(__builtin_bit_cast(h2, wv.x), w, acc.lo.x, false);
    acc.lo.y = __builtin_amdgcn_fdot2(__builtin_bit_cast(h2, wv.y), w, acc.lo.y, false);
    acc.hi.x = __builtin_amdgcn_fdot2(__builtin_bit_cast(h2, wv.z), w, acc.hi.x, false);
    acc.hi.y = __builtin_amdgcn_fdot2(__builtin_bit_cast(h2, wv.w), w, acc.hi.y, false);
}
#else
__device__ __forceinline__ void eval_row(f4& acc, uint4 u, float wA, float wB) {
    __half2 h0 = __builtin_bit_cast(__half2, u.x);
    __half2 h1 = __builtin_bit_cast(__half2, u.y);
    __half2 h2_ = __builtin_bit_cast(__half2, u.z);
    __half2 h3 = __builtin_bit_cast(__half2, u.w);
    acc.lo.x = fmaf(__half2float(h0.y), wB, fmaf(__half2float(h0.x), wA, acc.lo.x));
    acc.lo.y = fmaf(__half2float(h1.y), wB, fmaf(__half2float(h1.x), wA, acc.lo.y));
    acc.hi.x = fmaf(__half2float(h2_.y), wB, fmaf(__half2float(h2_.x), wA, acc.hi.x));
    acc.hi.y = fmaf(__half2float(h3.y), wB, fmaf(__half2float(h3.x), wA, acc.hi.y));
}

__device__ __forceinline__ void eval_plane(f4& acc, uint4 ua, uint4 ub,
                                           float wx, float wy) {
    float wB1 = wx * wy;
    float wB0 = wx - wB1;
    float wA1 = wy - wB1;
    float wA0 = 1.f - wx - wA1;
    eval_row(acc, ua, wA0, wB0);
    eval_row(acc, ub, wA1, wB1);
}

__device__ __forceinline__ void eval_rowp(f4& acc, uint4 u, unsigned pw) {
    __half2 hw = __builtin_bit_cast(__half2, pw);
    eval_row(acc, u, __half2float(hw.x), __half2float(hw.y));
}

__device__ __forceinline__ void dot2_4(f4& acc, uint4 wv, unsigned pw) {
    __half2 hw = __builtin_bit_cast(__half2, pw);
    float a0 = __half2float(hw.x), a1 = __half2float(hw.y);
    __half2 w0 = __builtin_bit_cast(__half2, wv.x);
    __half2 w1 = __builtin_bit_cast(__half2, wv.y);
    __half2 w2_ = __builtin_bit_cast(__half2, wv.z);
    __half2 w3 = __builtin_bit_cast(__half2, wv.w);
    acc.lo.x = fmaf(__half2float(w0.y), a1, fmaf(__half2float(w0.x), a0, acc.lo.x));
    acc.lo.y = fmaf(__half2float(w1.y), a1, fmaf(__half2float(w1.x), a0, acc.lo.y));
    acc.hi.x = fmaf(__half2float(w2_.y), a1, fmaf(__half2float(w2_.x), a0, acc.hi.x));
    acc.hi.y = fmaf(__half2float(w3.y), a1, fmaf(__half2float(w3.x), a0, acc.hi.y));
}
#endif

// LDS broadcast-slot strides (uints/floats), chosen so the 8 query-groups of a
// wave land in 8 distinct 4-bank windows on every read (conflict-free):
//   param slot:  base(q,s) = q*132 + s*16   -> bank window (4q+16s)%32
//   feat  slot:  base(q,kb) = q*36 + kb*4   -> bank window (4q+4kb)%32
//   wa    slot:  base(q,mb) = q*20 + mb*4   -> bank window (20q+4mb)%32
#define PAR_Q 132
#define FEAT_Q 36
#define WA_Q 20

__global__ __launch_bounds__(256)
void eda_main(const float* __restrict__ qp, const unsigned* __restrict__ tp,
              const float* __restrict__ Woff, const float* __restrict__ boff,
              const float* __restrict__ Ww, const float* __restrict__ bw,
              const float* __restrict__ Wc, const float* __restrict__ bvw,
              const float* __restrict__ bout, float* __restrict__ out) {
    // sWcat: COLUMN-PERMUTED, F32 (offsets are gradient-amplified; fp16 failed R4):
    //   col 4l+e = (e<3) ? W_off col (3l+e) : W_w col l
    __shared__ float    sWcat[32][32];
    __shared__ unsigned sWc2h[16][32];  // f16-pair packed Wc
    __shared__ float sbcat[32];
    __shared__ float sbvw[32];
    __shared__ float sbout[32];
    __shared__ unsigned sPar[32 * PAR_Q];   // per-query sample packages
    __shared__ float    sFeat[32 * FEAT_Q]; // per-query feature vector
    __shared__ unsigned sWa[32 * WA_Q];     // per-query packed wa

    int tid = threadIdx.x;
    int lane = tid & 7;
    int lane16 = lane << 4;
    int q  = tid >> 3;                            // query slot in block (0..31)
    int b  = blockIdx.x & 1;                      // XCD-parity batch split
    int qi = (blockIdx.x >> 1) * 32 + q;          // query within batch
    int qq = min(qi, NS - 1);

    const float* p = qp + ((size_t)b * NS + qq) * 3;
    float p0 = p[0], p1 = p[1], p2 = p[2];

    // wave-uniform plane base (batch select); taps use 32-bit byte offsets
    const char* tpb = (const char*)tp + ((size_t)(b * 3) << 21);

    // ---- issue feature tap loads early; they fly during LDS weight staging ----
    Coord fc = coord(p0, p1, p2);
    SampB fs;
    fs.u[0] = ldtap(tpb, fc.o0 + lane16); fs.u[1] = ldtap(tpb, fc.o1 + lane16);
    fs.u[2] = ldtap(tpb, fc.o2 + lane16); fs.u[3] = ldtap(tpb, fc.o3 + lane16);
    fs.u[4] = ldtap(tpb, fc.o4 + lane16); fs.u[5] = ldtap(tpb, fc.o5 + lane16);

    for (int i = tid; i < 1024; i += 256) {
        int k = i >> 5, j = i & 31, l2 = j >> 2, e = j & 3;
        sWcat[k][j] = (e < 3) ? Woff[k * 24 + 3 * l2 + e] : Ww[k * 8 + l2];
    }
    {
        int k2 = tid >> 5, j = tid & 31;
        sWc2h[k2][j]     = pk_rn(Wc[k2 * 64 + j],        Wc[k2 * 64 + 32 + j]);
        sWc2h[k2 + 8][j] = pk_rn(Wc[(k2 + 8) * 64 + j],  Wc[(k2 + 8) * 64 + 32 + j]);
    }
    if (tid < 32) {
        int l2 = tid >> 2, e = tid & 3;
        sbcat[tid] = (e < 3) ? boff[3 * l2 + e] : bw[l2];
        sbvw[tid]  = bvw[tid];
        sbout[tid] = bout[tid];
    }
    __syncthreads();

    // ---- feature ----
    f4 feat; feat.lo = (v2f){0.f, 0.f}; feat.hi = (v2f){0.f, 0.f};
    eval_plane(feat, fs.u[0], fs.u[1], fc.wc0, fc.wr2);   // XZ
    eval_plane(feat, fs.u[2], fs.u[3], fc.wc0, fc.wr1);   // XY
    eval_plane(feat, fs.u[4], fs.u[5], fc.wc1, fc.wr2);   // YZ

    // ---- stage feat to my query's LDS slot (same-wave consumers; no barrier) ----
    *(float4*)&sFeat[q * FEAT_Q + (lane << 2)] =
        make_float4(feat.lo.x, feat.lo.y, feat.hi.x, feat.hi.y);

    // ---- cat = feature @ [W_off | W_w] (permuted cols, F32) + bias ----
    f4 cat;
    cat.lo.x = sbcat[(lane << 2) + 0]; cat.lo.y = sbcat[(lane << 2) + 1];
    cat.hi.x = sbcat[(lane << 2) + 2]; cat.hi.y = sbcat[(lane << 2) + 3];
#pragma unroll
    for (int kb = 0; kb < 8; ++kb) {
        float4 fb = *(const float4*)&sFeat[q * FEAT_Q + (kb << 2)];
        float fe[4] = {fb.x, fb.y, fb.z, fb.w};
#pragma unroll
        for (int e = 0; e < 4; ++e) {
            int k = (kb << 2) + e;
            const v2f* wp = (const v2f*)&sWcat[k][lane << 2];
            v2f fc2 = {fe[e], fe[e]};
            cat.lo = __builtin_elementwise_fma(fc2, wp[0], cat.lo);
            cat.hi = __builtin_elementwise_fma(fc2, wp[1], cat.hi);
        }
    }

    // ---- per-lane precompute for MY sample (s = lane): offsets +
    //      wt-premultiplied packed corner weights; publish package to LDS ----
    Coord my = coord(p0 + cat.lo.x, p1 + cat.lo.y, p2 + cat.hi.x);
    float wt_my = cat.hi.y;
    unsigned m0, m1, m2, m3, m4, m5;
    { float wB1 = my.wc0 * my.wr2, wB0 = my.wc0 - wB1, wA1 = my.wr2 - wB1, wA0 = 1.f - my.wc0 - wA1;
      m0 = pack2(wA0 * wt_my, wB0 * wt_my); m1 = pack2(wA1 * wt_my, wB1 * wt_my); }  // XZ
    { float wB1 = my.wc0 * my.wr1, wB0 = my.wc0 - wB1, wA1 = my.wr1 - wB1, wA0 = 1.f - my.wc0 - wA1;
      m2 = pack2(wA0 * wt_my, wB0 * wt_my); m3 = pack2(wA1 * wt_my, wB1 * wt_my); }  // XY
    { float wB1 = my.wc1 * my.wr2, wB0 = my.wc1 - wB1, wA1 = my.wr2 - wB1, wA0 = 1.f - my.wc1 - wA1;
      m4 = pack2(wA0 * wt_my, wB0 * wt_my); m5 = pack2(wA1 * wt_my, wB1 * wt_my); }  // YZ
    {
        unsigned* slot = &sPar[q * PAR_Q + (lane << 4)];
        *(uint4*)(slot + 0) = make_uint4((unsigned)my.o0, (unsigned)my.o1,
                                         (unsigned)my.o2, (unsigned)my.o3);
        *(uint4*)(slot + 4) = make_uint4((unsigned)my.o4, (unsigned)my.o5, m0, m1);
        *(uint4*)(slot + 8) = make_uint4(m2, m3, m4, m5);
    }

    // wsum = sum of group's 8 sample weights (butterfly within 8-lane group)
    float wsum = wt_my;
    wsum += __shfl_xor(wsum, 1, 64);
    wsum += __shfl_xor(wsum, 2, 64);
    wsum += __shfl_xor(wsum, 4, 64);

    // ---- s-loop: read sample packages from LDS (broadcast within group),
    //      depth-1 tap prefetch; fdot2 accumulates straight into wa ----
    f4 wa; wa.lo = (v2f){0.f, 0.f}; wa.hi = (v2f){0.f, 0.f};
    SampB cur, nxt;
    uint4 pa, pb, pc;
    {
        const unsigned* sl = &sPar[q * PAR_Q];    // s = 0
        pa = *(const uint4*)(sl + 0);
        pb = *(const uint4*)(sl + 4);
        pc = *(const uint4*)(sl + 8);
        cur.u[0] = ldtap(tpb, (int)pa.x + lane16);
        cur.u[1] = ldtap(tpb, (int)pa.y + lane16);
        cur.u[2] = ldtap(tpb, (int)pa.z + lane16);
        cur.u[3] = ldtap(tpb, (int)pa.w + lane16);
        cur.u[4] = ldtap(tpb, (int)pb.x + lane16);
        cur.u[5] = ldtap(tpb, (int)pb.y + lane16);
    }
    unsigned mm0 = pb.z, mm1 = pb.w, mm2 = pc.x, mm3 = pc.y, mm4 = pc.z, mm5 = pc.w;
#pragma unroll
    for (int s = 0; s < SS; ++s) {
        if (s < SS - 1) {
            const unsigned* sl = &sPar[q * PAR_Q + ((s + 1) << 4)];
            pa = *(const uint4*)(sl + 0);
            pb = *(const uint4*)(sl + 4);
            pc = *(const uint4*)(sl + 8);
            nxt.u[0] = ldtap(tpb, (int)pa.x + lane16);
            nxt.u[1] = ldtap(tpb, (int)pa.y + lane16);
            nxt.u[2] = ldtap(tpb, (int)pa.z + lane16);
            nxt.u[3] = ldtap(tpb, (int)pa.w + lane16);
            nxt.u[4] = ldtap(tpb, (int)pb.x + lane16);
            nxt.u[5] = ldtap(tpb, (int)pb.y + lane16);
        }
        eval_rowp(wa, cur.u[0], mm0);
        eval_rowp(wa, cur.u[1], mm1);
        eval_rowp(wa, cur.u[2], mm2);
        eval_rowp(wa, cur.u[3], mm3);
        eval_rowp(wa, cur.u[4], mm4);
        eval_rowp(wa, cur.u[5], mm5);
        if (s < SS - 1) {
            cur = nxt;
            mm0 = pb.z; mm1 = pb.w; mm2 = pc.x; mm3 = pc.y; mm4 = pc.z; mm5 = pc.w;
        }
    }

    // ---- out = wa @ (W_v@W_out) + wsum*(b_v@W_out) + b_out + feature ----
    f4 o;
    v2f ws2 = {wsum, wsum};
    {
        v2f bo  = {sbout[(lane << 2) + 0], sbout[(lane << 2) + 1]};
        v2f bv2 = {sbvw[(lane << 2) + 0], sbvw[(lane << 2) + 1]};
        o.lo = __builtin_elementwise_fma(ws2, bv2, bo) + feat.lo;
        v2f bo2 = {sbout[(lane << 2) + 2], sbout[(lane << 2) + 3]};
        v2f bv3 = {sbvw[(lane << 2) + 2], sbvw[(lane << 2) + 3]};
        o.hi = __builtin_elementwise_fma(ws2, bv3, bo2) + feat.hi;
    }
    // wa packed as f16 pairs (final non-amplified linear, err ~0.005);
    // uint j of the slot holds channels (2j, 2j+1) -> matches sWc2h row order.
    {
        unsigned pkLo = pack2(wa.lo.x, wa.lo.y);   // channels 4l, 4l+1
        unsigned pkHi = pack2(wa.hi.x, wa.hi.y);   // channels 4l+2, 4l+3
        *(uint2*)&sWa[q * WA_Q + (lane << 1)] = make_uint2(pkLo, pkHi);
    }
#pragma unroll
    for (int mb = 0; mb < 4; ++mb) {
        uint4 wq = *(const uint4*)&sWa[q * WA_Q + (mb << 2)];
        unsigned we[4] = {wq.x, wq.y, wq.z, wq.w};
#pragma unroll
        for (int e = 0; e < 4; ++e) {
            int k2 = (mb << 2) + e;
            const uint4 wv = *(const uint4*)&sWc2h[k2][lane << 2];
            dot2_4(o, wv, we[e]);
        }
    }

    if (qi < NS) {
        float* dst = out + ((size_t)b * NS + qi) * 32 + (lane << 2);
        *(float4*)dst = make_float4(o.lo.x, o.lo.y, o.hi.x, o.hi.y);
    }
}

extern "C" void kernel_launch(void* const* d_in, const int* in_sizes, int n_in,
                              void* d_out, int out_size, void* d_ws, size_t ws_size,
                              hipStream_t stream) {
    const float* qp   = (const float*)d_in[0];
    const float* cxz  = (const float*)d_in[1];
    const float* cxy  = (const float*)d_in[2];
    const float* cyz  = (const float*)d_in[3];
    const float* Woff = (const float*)d_in[4];
    const float* boff = (const float*)d_in[5];
    const float* Ww   = (const float*)d_in[6];
    const float* bw   = (const float*)d_in[7];
    const float* Wv   = (const float*)d_in[8];
    const float* bv   = (const float*)d_in[9];
    const float* Wout = (const float*)d_in[10];
    const float* bout = (const float*)d_in[11];
    float* out = (float*)d_out;

    unsigned* tp = (unsigned*)d_ws;
    float* Wc  = (float*)((char*)d_ws + (size_t)BS * 3 * RR * RR * CCH * 4);
    float* bvw = Wc + 1024;

    prep<<<BS * 3 * RR + 4, 256, 0, stream>>>(cxz, cxy, cyz, Wv, bv, Wout, tp, Wc, bvw);
    // even blockIdx -> batch 0, odd -> batch 1 (round-robin block->XCD dispatch
    // biases each XCD toward one batch's planes).
    int blocks_per_batch = (NS + 31) / 32;   // 32 queries per 256-thread block
    eda_main<<<2 * blocks_per_batch, 256, 0, stream>>>(qp, tp, Woff, boff, Ww, bw,
                                                       Wc, bvw, bout, out);
}